// Round 3
// baseline (190.018 us; speedup 1.0000x reference)
//
#include <hip/hip_runtime.h>

// InvertAffine: per sample, full = [[I+M, t],[0,1]] (4x4). Inverse is
// [[B, -B t],[0,1]] with B = (I+M)^{-1} via 3x3 cofactors.
// Memory-bound: 2M * 96 B = 192 MB total logical traffic, floor ~30 us.
//
// R1 post-mortem: coalesced-via-LDS == strided-direct (both ~58 us, 2.5 TB/s)
// -> access pattern is NOT the limiter. Shared trait: one-shot burst blocks
// (3 loads -> barrier -> compute -> barrier -> store -> exit) can't keep
// enough reads in flight (Little's law: ~900 KB needed device-wide at 900 cyc
// HBM latency). fillBufferAligned (grid-stride streaming) hits 6.6 TB/s on
// the same machine.
//
// R2: persistent grid-stride streaming, no LDS/barriers. 4 samples per
// iteration per thread = 12 independent float4 loads (192 B/lane in flight),
// 1024 blocks x 256 threads, ~2 loop iterations -> steady-state pipe.

__global__ __launch_bounds__(256) void invert_affine_kernel(
    const float4* __restrict__ in, float4* __restrict__ out, int b) {
  const int tid = blockIdx.x * blockDim.x + threadIdx.x;
  const int nthreads = gridDim.x * blockDim.x;
  const int ngroups = (b + 3) >> 2;  // groups of 4 samples = 12 float4

  for (int g = tid; g < ngroups; g += nthreads) {
    const int f4base = g * 12;
    const int rem = b - g * 4;            // samples in this group (4 except tail)
    float4 v[12];

    if (rem >= 4) {
#pragma unroll
      for (int k = 0; k < 12; ++k) v[k] = in[f4base + k];  // 12 loads in flight

#pragma unroll
      for (int j = 0; j < 4; ++j) {
        float4 r0 = v[3 * j + 0], r1 = v[3 * j + 1], r2 = v[3 * j + 2];

        float a00 = r0.x + 1.0f, a01 = r0.y,        a02 = r0.z,        t0 = r0.w;
        float a10 = r1.x,        a11 = r1.y + 1.0f, a12 = r1.z,        t1 = r1.w;
        float a20 = r2.x,        a21 = r2.y,        a22 = r2.z + 1.0f, t2 = r2.w;

        float b00 = a11 * a22 - a12 * a21;
        float b01 = a02 * a21 - a01 * a22;
        float b02 = a01 * a12 - a02 * a11;
        float b10 = a12 * a20 - a10 * a22;
        float b11 = a00 * a22 - a02 * a20;
        float b12 = a02 * a10 - a00 * a12;
        float b20 = a10 * a21 - a11 * a20;
        float b21 = a01 * a20 - a00 * a21;
        float b22 = a00 * a11 - a01 * a10;

        float det = a00 * b00 + a01 * b10 + a02 * b20;
        float rdet = 1.0f / det;

        b00 *= rdet; b01 *= rdet; b02 *= rdet;
        b10 *= rdet; b11 *= rdet; b12 *= rdet;
        b20 *= rdet; b21 *= rdet; b22 *= rdet;

        v[3 * j + 0] = make_float4(b00 - 1.0f, b01, b02,
                                   -(b00 * t0 + b01 * t1 + b02 * t2));
        v[3 * j + 1] = make_float4(b10, b11 - 1.0f, b12,
                                   -(b10 * t0 + b11 * t1 + b12 * t2));
        v[3 * j + 2] = make_float4(b20, b21, b22 - 1.0f,
                                   -(b20 * t0 + b21 * t1 + b22 * t2));
      }

#pragma unroll
      for (int k = 0; k < 12; ++k) out[f4base + k] = v[k];
    } else {
      // tail group (b not divisible by 4) — scalar per-sample path
      for (int j = 0; j < rem; ++j) {
        const int fb = f4base + 3 * j;
        float4 r0 = in[fb + 0], r1 = in[fb + 1], r2 = in[fb + 2];

        float a00 = r0.x + 1.0f, a01 = r0.y,        a02 = r0.z,        t0 = r0.w;
        float a10 = r1.x,        a11 = r1.y + 1.0f, a12 = r1.z,        t1 = r1.w;
        float a20 = r2.x,        a21 = r2.y,        a22 = r2.z + 1.0f, t2 = r2.w;

        float b00 = a11 * a22 - a12 * a21;
        float b01 = a02 * a21 - a01 * a22;
        float b02 = a01 * a12 - a02 * a11;
        float b10 = a12 * a20 - a10 * a22;
        float b11 = a00 * a22 - a02 * a20;
        float b12 = a02 * a10 - a00 * a12;
        float b20 = a10 * a21 - a11 * a20;
        float b21 = a01 * a20 - a00 * a21;
        float b22 = a00 * a11 - a01 * a10;

        float det = a00 * b00 + a01 * b10 + a02 * b20;
        float rdet = 1.0f / det;

        b00 *= rdet; b01 *= rdet; b02 *= rdet;
        b10 *= rdet; b11 *= rdet; b12 *= rdet;
        b20 *= rdet; b21 *= rdet; b22 *= rdet;

        out[fb + 0] = make_float4(b00 - 1.0f, b01, b02,
                                  -(b00 * t0 + b01 * t1 + b02 * t2));
        out[fb + 1] = make_float4(b10, b11 - 1.0f, b12,
                                  -(b10 * t0 + b11 * t1 + b12 * t2));
        out[fb + 2] = make_float4(b20, b21, b22 - 1.0f,
                                  -(b20 * t0 + b21 * t1 + b22 * t2));
      }
    }
  }
}

extern "C" void kernel_launch(void* const* d_in, const int* in_sizes, int n_in,
                              void* d_out, int out_size, void* d_ws, size_t ws_size,
                              hipStream_t stream) {
  const float4* trf = (const float4*)d_in[0];
  float4* out = (float4*)d_out;
  int b = in_sizes[0] / 12;  // 2,000,000 samples
  // persistent-ish streaming grid: 1024 blocks = 4 blocks/CU, ~2 groups/thread
  invert_affine_kernel<<<1024, 256, 0, stream>>>(trf, out, b);
}

// Round 6
// 167.738 us; speedup vs baseline: 1.1328x; 1.1328x over previous
//
#include <hip/hip_runtime.h>

// InvertAffine: per sample, full = [[I+M, t],[0,1]] (4x4). Inverse is
// [[B, -B t],[0,1]] with B = (I+M)^{-1} via 3x3 cofactors.
// 192 MB logical traffic; write-only fill hits 6.6 TB/s on this machine.
//
// R1/R2 post-mortem: coalescing, LDS staging, streaming shape, occupancy all
// neutral -> stuck at ~58 us (3.3 TB/s combined). Nothing CU-side saturated
// (VALU 8%, vmem 5 B/cyc/CU, 0 bank conflicts). Suspect: store-miss RFO in
// L2 (output lines evicted to L3 after poison; each store pulls the line
// before overwriting) doubling internal write traffic.
// R3/R5: nontemporal stores (nt flag -> no allocate/RFO). Single change vs
// R1. R5 fixes the compile error: the builtin needs a native clang vector
// type, not HIP_vector_type<float,4> — cast through ext_vector_type(4).

typedef float nfloat4 __attribute__((ext_vector_type(4)));

__global__ __launch_bounds__(256, 8) void invert_affine_kernel(
    const float4* __restrict__ in, float4* __restrict__ out, int b) {
  __shared__ float4 buf[768];  // 256 samples * 3 float4 = 12 KB

  const int tid = threadIdx.x;
  const int base_s = blockIdx.x * 256;
  const int base_f4 = base_s * 3;
  const int n_f4 = b * 3;

  // coalesced global -> LDS
#pragma unroll
  for (int k = 0; k < 3; ++k) {
    int idx = base_f4 + k * 256 + tid;
    if (idx < n_f4) buf[k * 256 + tid] = in[idx];
  }
  __syncthreads();

  const int s = base_s + tid;
  if (s < b) {
    float4 r0 = buf[tid * 3 + 0];
    float4 r1 = buf[tid * 3 + 1];
    float4 r2 = buf[tid * 3 + 2];

    float a00 = r0.x + 1.0f, a01 = r0.y,        a02 = r0.z,        t0 = r0.w;
    float a10 = r1.x,        a11 = r1.y + 1.0f, a12 = r1.z,        t1 = r1.w;
    float a20 = r2.x,        a21 = r2.y,        a22 = r2.z + 1.0f, t2 = r2.w;

    float b00 = a11 * a22 - a12 * a21;
    float b01 = a02 * a21 - a01 * a22;
    float b02 = a01 * a12 - a02 * a11;
    float b10 = a12 * a20 - a10 * a22;
    float b11 = a00 * a22 - a02 * a20;
    float b12 = a02 * a10 - a00 * a12;
    float b20 = a10 * a21 - a11 * a20;
    float b21 = a01 * a20 - a00 * a21;
    float b22 = a00 * a11 - a01 * a10;

    float det = a00 * b00 + a01 * b10 + a02 * b20;
    float rdet = 1.0f / det;

    b00 *= rdet; b01 *= rdet; b02 *= rdet;
    b10 *= rdet; b11 *= rdet; b12 *= rdet;
    b20 *= rdet; b21 *= rdet; b22 *= rdet;

    buf[tid * 3 + 0] = make_float4(b00 - 1.0f, b01, b02,
                                   -(b00 * t0 + b01 * t1 + b02 * t2));
    buf[tid * 3 + 1] = make_float4(b10, b11 - 1.0f, b12,
                                   -(b10 * t0 + b11 * t1 + b12 * t2));
    buf[tid * 3 + 2] = make_float4(b20, b21, b22 - 1.0f,
                                   -(b20 * t0 + b21 * t1 + b22 * t2));
  }
  __syncthreads();

  // coalesced LDS -> global, nontemporal (no L2 allocate / RFO)
#pragma unroll
  for (int k = 0; k < 3; ++k) {
    int idx = base_f4 + k * 256 + tid;
    if (idx < n_f4) {
      float4 vv = buf[k * 256 + tid];
      nfloat4 nv;
      nv.x = vv.x; nv.y = vv.y; nv.z = vv.z; nv.w = vv.w;
      __builtin_nontemporal_store(nv, (nfloat4*)&out[idx]);
    }
  }
}

extern "C" void kernel_launch(void* const* d_in, const int* in_sizes, int n_in,
                              void* d_out, int out_size, void* d_ws, size_t ws_size,
                              hipStream_t stream) {
  const float4* trf = (const float4*)d_in[0];
  float4* out = (float4*)d_out;
  int b = in_sizes[0] / 12;  // 2,000,000 samples
  const int threads = 256;
  int blocks = (b + threads - 1) / threads;  // 7813
  invert_affine_kernel<<<blocks, threads, 0, stream>>>(trf, out, b);
}